// Round 15
// baseline (95.638 us; speedup 1.0000x reference)
//
#include <hip/hip_runtime.h>

#define BB  2
#define TT  2048
#define EE  1024
#define HH  16
#define DH  64
#define MM1 1024
#define MM2 256

// softmax scale log2(e)/8 folded into K at conversion time
#define KSCL 0.18033688011112042f

typedef unsigned short u16;
typedef unsigned int   u32;
typedef __bf16 bf16x2 __attribute__((ext_vector_type(2)));
typedef __bf16 bf16x8 __attribute__((ext_vector_type(8)));
typedef float  f32x4  __attribute__((ext_vector_type(4)));

static __device__ __forceinline__ u32 f2bf_bits(float x) {
    union { float f; u32 u; } v; v.f = x;
    return (v.u + 0x7FFFu + ((v.u >> 16) & 1u)) >> 16;   // RNE
}
static __device__ __forceinline__ u32 pkbf(float a, float b) {
    bf16x2 t; t.x = (__bf16)a; t.y = (__bf16)b;          // v_cvt_pk_bf16_f32
    return __builtin_bit_cast(u32, t);
}
// raw v_exp_f32 (2^x): bypasses OCML exp2f wrapper ops
static __device__ __forceinline__ float fexp2(float x) {
    float r; asm("v_exp_f32 %0, %1" : "=v"(r) : "v"(x)); return r;
}
// tile addressing: 128-byte rows (64 bf16), XOR swizzle -> bank-uniform frag reads
static __device__ __forceinline__ int swz(int row, int cb) {
    return row * 128 + (cb ^ ((row & 7) << 4));
}
static __device__ __forceinline__ void gload16(void* lds, const void* g) {
    __builtin_amdgcn_global_load_lds((const __attribute__((address_space(1))) u32*)g,
                                     (__attribute__((address_space(3))) u32*)lds, 16, 0, 0);
}

// ---------------------------------------------------------------------------
// One fused conversion dispatch. z=0: x, z=1: Wq, z=2: Wproj (row-major f32
// [R][1024] -> bf16 swizzled 128x64 tile blobs). z=3: K1 (scaled by KSCL),
// z=4: V1 (transposed to [d][m]), z=5: K2, z=6: V2 (per-(b,h) 8KB tile blobs).
// ---------------------------------------------------------------------------
__global__ __launch_bounds__(256) void conv_all(const float* __restrict__ x,
                                                const float* __restrict__ wq,
                                                const float* __restrict__ wp,
                                                const float* __restrict__ K1, const float* __restrict__ V1,
                                                const float* __restrict__ K2, const float* __restrict__ V2,
                                                char* __restrict__ xs, char* __restrict__ wqs, char* __restrict__ wps,
                                                char* __restrict__ Kb1, char* __restrict__ Vb1,
                                                char* __restrict__ Kb2, char* __restrict__ Vb2)
{
    __shared__ u16 T[64 * 72];
    const int z = blockIdx.z, bx = blockIdx.x, by = blockIdx.y;
    const int tid = threadIdx.x;
    if (z < 3) {
        if (by >= 16) return;
        if (z > 0 && bx >= 8) return;
        const float* A = z == 0 ? x : (z == 1 ? wq : wp);
        char* Ab = z == 0 ? xs : (z == 1 ? wqs : wps);
        const int row = tid >> 1, half = tid & 1;
        const float* src = A + ((size_t)bx * 128 + row) * EE + by * 64 + half * 32;
        char* dst = Ab + ((size_t)(bx * 16 + by)) * 16384;
        float v[32];
        #pragma unroll
        for (int i = 0; i < 8; ++i) *(float4*)&v[i * 4] = ((const float4*)src)[i];
        u32 pk[16];
        #pragma unroll
        for (int j = 0; j < 16; ++j) pk[j] = pkbf(v[2 * j], v[2 * j + 1]);
        #pragma unroll
        for (int j = 0; j < 4; ++j)
            *(uint4*)(dst + swz(row, half * 64 + j * 16)) = *(uint4*)&pk[j * 4];
        return;
    }
    const int zz = z - 3;
    const int M = (zz >= 2) ? MM2 : MM1;
    if (bx * 64 >= M) return;
    const int isV = zz & 1;
    const float* src4[4] = { K1, V1, K2, V2 };
    char* dst4[4] = { Kb1, Vb1, Kb2, Vb2 };
    const int b = by >> 4, h = by & 15;
    char* dst = dst4[zz] + ((size_t)by * (M / 64) + bx) * 8192;
    const float* src = src4[zz] + ((size_t)b * M + (size_t)bx * 64) * EE + h * DH;
    const int m = tid >> 2, q = tid & 3;
    const float* s = src + (size_t)m * EE + q * 16;
    float v[16];
    #pragma unroll
    for (int i = 0; i < 4; ++i) *(float4*)&v[i * 4] = ((const float4*)s)[i];
    if (!isV) {
        u32 pk[8];
        #pragma unroll
        for (int j = 0; j < 8; ++j) pk[j] = pkbf(v[2 * j] * KSCL, v[2 * j + 1] * KSCL);
        *(uint4*)(dst + swz(m, q * 32))      = *(uint4*)&pk[0];
        *(uint4*)(dst + swz(m, q * 32 + 16)) = *(uint4*)&pk[4];
    } else {
        #pragma unroll
        for (int j = 0; j < 16; ++j) T[(q * 16 + j) * 72 + m] = (u16)f2bf_bits(v[j]);
        __syncthreads();
        const int d = tid >> 2, qq = tid & 3;
        uint4 a0 = *(const uint4*)((const char*)T + d * 144 + qq * 32);
        uint4 a1 = *(const uint4*)((const char*)T + d * 144 + qq * 32 + 16);
        *(uint4*)(dst + swz(d, qq * 32))      = a0;
        *(uint4*)(dst + swz(d, qq * 32 + 16)) = a1;
    }
}

// ---------------------------------------------------------------------------
// bf16 MFMA GEMM, 512 thr / 8 waves, 128x64 tile, BK=64, grid 512 (16
// waves/CU). A: LDS double-buffered via global_load_lds. B: NO LDS — frags
// read global->reg from the pre-swizzled blob (per-XCD B-slice is 0.5MB,
// L2-resident). B loads are issued BEFORE the A-prefetch each iteration
// (sched_barrier fence) so FIFO vmcnt waits only on B, never draining the
// prefetch (R8-proven ordering). Removes 8KB/kt staging + 16 ds_reads/kt.
// FINAL: *sigmoid(gate), f32 out; else bf16 row-major (Q).
// ---------------------------------------------------------------------------
template<bool FINAL>
__global__ __launch_bounds__(512) void gemm_swz(const char* __restrict__ Ab,
                                                const char* __restrict__ Bb,
                                                void* __restrict__ Cout,
                                                const float* __restrict__ gate)
{
    constexpr int NKT = EE / 64;
    __shared__ char As[2][16384];
    const int tid = threadIdx.x, lane = tid & 63, w = tid >> 6;
    const int wr = w >> 1, wc = w & 1, g = lane >> 4, ln = lane & 15;
    int lin = blockIdx.y * 32 + blockIdx.x;            // 0..511
    lin = (lin & 7) * 64 + (lin >> 3);                 // bijective XCD chunking
    const int bmi = lin & 31, bni = lin >> 5;
    const char* Abase = Ab + (size_t)bmi * NKT * 16384;
    const char* Bbase = Bb + (size_t)(bni >> 1) * NKT * 16384 + (size_t)(bni & 1) * 8192;
    int bswz[2][2];
    #pragma unroll
    for (int kh = 0; kh < 2; ++kh)
        #pragma unroll
        for (int j = 0; j < 2; ++j)
            bswz[kh][j] = swz(wc * 32 + j * 16 + ln, kh * 64 + g * 16);
    gload16(As[0] + tid * 16,        Abase + tid * 16);
    gload16(As[0] + tid * 16 + 8192, Abase + tid * 16 + 8192);
    f32x4 acc[2][2] = {};
    for (int kt = 0; kt < NKT; ++kt) {
        const int cur = kt & 1;
        __syncthreads();                               // A tile kt staged
        // 1) B-frag global loads for THIS kt (issued before the prefetch)
        bf16x8 bfr[2][2];
        #pragma unroll
        for (int kh = 0; kh < 2; ++kh)
            #pragma unroll
            for (int j = 0; j < 2; ++j)
                bfr[kh][j] = *(const bf16x8*)(Bbase + (size_t)kt * 16384 + bswz[kh][j]);
        __builtin_amdgcn_sched_barrier(0);             // keep B-loads older than prefetch
        // 2) A-prefetch for kt+1
        if (kt + 1 < NKT) {
            const char* an = Abase + (size_t)(kt + 1) * 16384;
            gload16(As[cur ^ 1] + tid * 16,        an + tid * 16);
            gload16(As[cur ^ 1] + tid * 16 + 8192, an + tid * 16 + 8192);
        }
        // 3) A-frags from LDS + MFMA
        #pragma unroll
        for (int kh = 0; kh < 2; ++kh) {
            bf16x8 af[2];
            #pragma unroll
            for (int i = 0; i < 2; ++i)
                af[i] = *(const bf16x8*)(As[cur] + swz(wr * 32 + i * 16 + ln, kh * 64 + g * 16));
            #pragma unroll
            for (int i = 0; i < 2; ++i)
                #pragma unroll
                for (int j = 0; j < 2; ++j)
                    acc[i][j] = __builtin_amdgcn_mfma_f32_16x16x32_bf16(af[i], bfr[kh][j], acc[i][j], 0, 0, 0);
        }
    }
    float alpha = 1.0f;
    if constexpr (FINAL) alpha = 1.0f / (1.0f + __expf(-gate[0]));
    #pragma unroll
    for (int i = 0; i < 2; ++i)
        #pragma unroll
        for (int r = 0; r < 4; ++r) {
            const int row = bmi * 128 + wr * 32 + i * 16 + g * 4 + r;
            #pragma unroll
            for (int j = 0; j < 2; ++j) {
                const int col = bni * 64 + wc * 32 + j * 16 + ln;
                if constexpr (FINAL) ((float*)Cout)[(size_t)row * EE + col] = acc[i][j][r] * alpha;
                else ((u16*)Cout)[(size_t)row * EE + col] = (u16)f2bf_bits(acc[i][j][r]);
            }
        }
}

// ---------------------------------------------------------------------------
// Fused two-source attention, 8 waves x 16 q-rows (512 threads) — EXACT R9
// structure (measured ~1.1x its per-CU LDS-traffic floor at 4 waves/SIMD;
// R12/R13 decomposition variants both regressed). Unchanged from R14.
// ---------------------------------------------------------------------------
__global__ __launch_bounds__(512) void attn2(const u16* __restrict__ Qb,
                                             const char* __restrict__ Kb1, const char* __restrict__ Vb1,
                                             const char* __restrict__ Kb2, const char* __restrict__ Vb2,
                                             char* __restrict__ Ctxs)
{
    __shared__ char KV[2][16384];        // per buf: +0 K tile (8KB), +8192 V^T tile (8KB)
    __shared__ char Ps[8][2048];         // per-wave P: 16 t-rows x 128B, swizzled
    const int tid = threadIdx.x, lane = tid & 63, w = tid >> 6;
    const int g = lane >> 4, ln = lane & 15;
    const int lnx = (ln & 7) << 4;
    int lin = blockIdx.y * 16 + blockIdx.x;            // 0..511
    lin = (lin & 7) * 64 + (lin >> 3);                 // XCD chunking: 4 bh per XCD
    const int bx = lin & 15, bh = lin >> 4;
    const int b = bh >> 4, h = bh & 15;
    const int t0 = bx * 128;
    constexpr int NT1 = MM1 / 64, NT = NT1 + MM2 / 64; // 16, 20

    bf16x8 qf[2];
    #pragma unroll
    for (int kh = 0; kh < 2; ++kh)
        qf[kh] = *(const bf16x8*)(Qb + ((size_t)(b * TT + t0 + w * 16 + ln)) * EE
                                  + h * DH + kh * 32 + g * 8);

    const char* Kbase[2] = { Kb1 + (size_t)bh * (MM1 / 64) * 8192, Kb2 + (size_t)bh * (MM2 / 64) * 8192 };
    const char* Vbase[2] = { Vb1 + (size_t)bh * (MM1 / 64) * 8192, Vb2 + (size_t)bh * (MM2 / 64) * 8192 };

    // prologue: stage K+V tile 0 (512 thr x 16B covers each 8KB tile)
    gload16(KV[0] + tid * 16,        Kbase[0] + tid * 16);
    gload16(KV[0] + 8192 + tid * 16, Vbase[0] + tid * 16);

    f32x4 oacc[4] = {}, outacc[4] = {};
    float psum = 0.0f;

    for (int ti = 0; ti < NT; ++ti) {
        const int cur = ti & 1;
        __syncthreads();                 // K+V tile ti staged; all waves done with KV[cur^1]
        if (ti + 1 < NT) {
            const int nx = ti + 1;
            const int pn = (nx >= NT1) ? 1 : 0, mtn = pn ? nx - NT1 : nx;
            gload16(KV[cur ^ 1] + tid * 16,        Kbase[pn] + (size_t)mtn * 8192 + tid * 16);
            gload16(KV[cur ^ 1] + 8192 + tid * 16, Vbase[pn] + (size_t)mtn * 8192 + tid * 16);
        }
        // ---- QK^T swapped: s[f] = S^T[m = f*16+4g+r][t = w*16+ln]
        f32x4 s[4] = {};
        __builtin_amdgcn_s_setprio(1);
        #pragma unroll
        for (int kh = 0; kh < 2; ++kh)
            #pragma unroll
            for (int f = 0; f < 4; ++f) {
                const bf16x8 kf = *(const bf16x8*)(KV[cur] + swz(f * 16 + ln, kh * 64 + g * 16));
                s[f] = __builtin_amdgcn_mfma_f32_16x16x32_bf16(kf, qf[kh], s[f], 0, 0, 0);
            }
        __builtin_amdgcn_s_setprio(0);
        // ---- static softmax: p = exp2(s) (scale folded into K); pack along m
        #pragma unroll
        for (int f = 0; f < 4; ++f) {
            const float p0 = fexp2(s[f][0]);
            const float p1 = fexp2(s[f][1]);
            const float p2 = fexp2(s[f][2]);
            const float p3 = fexp2(s[f][3]);
            psum += (p0 + p1) + (p2 + p3);
            uint2 w2; w2.x = pkbf(p0, p1); w2.y = pkbf(p2, p3);
            *(uint2*)(Ps[w] + ln * 128 + ((f * 32 + g * 8) ^ lnx)) = w2;
        }
        // ---- PV: oacc[f][r] = O[t = w*16+ln][d = f*16+4g+r]
        __builtin_amdgcn_s_setprio(1);
        #pragma unroll
        for (int ks = 0; ks < 2; ++ks) {
            const bf16x8 pf = *(const bf16x8*)(Ps[w] + ln * 128 + ((ks * 64 + g * 16) ^ lnx));
            #pragma unroll
            for (int f = 0; f < 4; ++f) {
                const bf16x8 vf = *(const bf16x8*)(KV[cur] + 8192 + swz(f * 16 + ln, ks * 64 + g * 16));
                oacc[f] = __builtin_amdgcn_mfma_f32_16x16x32_bf16(vf, pf, oacc[f], 0, 0, 0);
            }
        }
        __builtin_amdgcn_s_setprio(0);
        // ---- pass boundary: normalize (2 shfl) and reset
        if (ti == NT1 - 1 || ti == NT - 1) {
            float t = psum;
            t += __shfl_xor(t, 16);
            t += __shfl_xor(t, 32);
            const float inv = 1.0f / t;
            #pragma unroll
            for (int f = 0; f < 4; ++f)
                #pragma unroll
                for (int r = 0; r < 4; ++r) {
                    outacc[f][r] += oacc[f][r] * inv;
                    oacc[f][r] = 0.0f;
                }
            psum = 0.0f;
        }
    }

    // ---- epilogue: swizzled ctx blob in LDS (16KB = KV[0]), then linear copy
    __syncthreads();
    char* eb = &KV[0][0];
    #pragma unroll
    for (int f = 0; f < 4; ++f) {
        uint2 w2;
        w2.x = pkbf(outacc[f][0], outacc[f][1]);
        w2.y = pkbf(outacc[f][2], outacc[f][3]);
        *(uint2*)(eb + (w * 16 + ln) * 128 + ((f * 32 + g * 8) ^ lnx)) = w2;
    }
    __syncthreads();
    char* blob = Ctxs + ((size_t)((b * 16 + bx) * 16 + h)) * 16384;
    #pragma unroll
    for (int i = 0; i < 2; ++i)
        *(uint4*)(blob + tid * 16 + i * 8192) = *(const uint4*)(eb + tid * 16 + i * 8192);
}

// ---------------------------------------------------------------------------
extern "C" void kernel_launch(void* const* d_in, const int* in_sizes, int n_in,
                              void* d_out, int out_size, void* d_ws, size_t ws_size,
                              hipStream_t stream) {
    const float* x    = (const float*)d_in[0];
    const float* K1   = (const float*)d_in[1];
    const float* V1   = (const float*)d_in[2];
    const float* K2   = (const float*)d_in[3];
    const float* V2   = (const float*)d_in[4];
    const float* Wq   = (const float*)d_in[5];
    const float* Wp   = (const float*)d_in[6];
    const float* gate = (const float*)d_in[7];
    float* out = (float*)d_out;

    char* ws  = (char*)d_ws;
    char* Xs  = ws;                        // 8MB swizzled x; later reused as ctx blobs
    char* Wqs = ws + (8u  << 20);          // 2MB
    char* Wps = ws + (10u << 20);          // 2MB
    u16*  Qb  = (u16*)(ws + (12u << 20));  // 8MB bf16 Q (row-major)
    char* Kb1 = ws + (20u << 20);          // 4MB
    char* Vb1 = ws + (24u << 20);          // 4MB
    char* Kb2 = ws + (28u << 20);          // 1MB
    char* Vb2 = ws + (29u << 20);          // 1MB  (total 30MB)

    dim3 blk(256);
    conv_all<<<dim3(32, 32, 7), blk, 0, stream>>>(x, Wq, Wp, K1, V1, K2, V2,
                                                  Xs, Wqs, Wps, Kb1, Vb1, Kb2, Vb2);
    gemm_swz<false><<<dim3(32, 16), dim3(512), 0, stream>>>(Xs, Wqs, Qb, nullptr);
    attn2<<<dim3(16, 32), dim3(512), 0, stream>>>(Qb, Kb1, Vb1, Kb2, Vb2, Xs /*ctx blobs*/);
    gemm_swz<true><<<dim3(32, 16), dim3(512), 0, stream>>>(Xs, Wps, out, gate);
}

// Round 16
// 86.575 us; speedup vs baseline: 1.1047x; 1.1047x over previous
//
#include <hip/hip_runtime.h>

#define BB  2
#define TT  2048
#define EE  1024
#define HH  16
#define DH  64
#define MM1 1024
#define MM2 256

// softmax scale log2(e)/8 folded into K at conversion time
#define KSCL 0.18033688011112042f

typedef unsigned short u16;
typedef unsigned int   u32;
typedef __bf16 bf16x2 __attribute__((ext_vector_type(2)));
typedef __bf16 bf16x8 __attribute__((ext_vector_type(8)));
typedef float  f32x4  __attribute__((ext_vector_type(4)));

static __device__ __forceinline__ u32 f2bf_bits(float x) {
    union { float f; u32 u; } v; v.f = x;
    return (v.u + 0x7FFFu + ((v.u >> 16) & 1u)) >> 16;   // RNE
}
static __device__ __forceinline__ u32 pkbf(float a, float b) {
    bf16x2 t; t.x = (__bf16)a; t.y = (__bf16)b;          // v_cvt_pk_bf16_f32
    return __builtin_bit_cast(u32, t);
}
// raw v_exp_f32 (2^x): bypasses OCML exp2f wrapper ops
static __device__ __forceinline__ float fexp2(float x) {
    float r; asm("v_exp_f32 %0, %1" : "=v"(r) : "v"(x)); return r;
}
// tile addressing: 128-byte rows (64 bf16), XOR swizzle -> bank-uniform frag reads
static __device__ __forceinline__ int swz(int row, int cb) {
    return row * 128 + (cb ^ ((row & 7) << 4));
}
static __device__ __forceinline__ void gload16(void* lds, const void* g) {
    __builtin_amdgcn_global_load_lds((const __attribute__((address_space(1))) u32*)g,
                                     (__attribute__((address_space(3))) u32*)lds, 16, 0, 0);
}

// ---------------------------------------------------------------------------
// One fused conversion dispatch. z=0: x, z=1: Wq, z=2: Wproj (row-major f32
// [R][1024] -> bf16 swizzled 128x64 tile blobs). z=3: K1 (scaled by KSCL),
// z=4: V1 (transposed to [d][m]), z=5: K2, z=6: V2 (per-(b,h) 8KB tile blobs).
// ---------------------------------------------------------------------------
__global__ __launch_bounds__(256) void conv_all(const float* __restrict__ x,
                                                const float* __restrict__ wq,
                                                const float* __restrict__ wp,
                                                const float* __restrict__ K1, const float* __restrict__ V1,
                                                const float* __restrict__ K2, const float* __restrict__ V2,
                                                char* __restrict__ xs, char* __restrict__ wqs, char* __restrict__ wps,
                                                char* __restrict__ Kb1, char* __restrict__ Vb1,
                                                char* __restrict__ Kb2, char* __restrict__ Vb2)
{
    __shared__ u16 T[64 * 72];
    const int z = blockIdx.z, bx = blockIdx.x, by = blockIdx.y;
    const int tid = threadIdx.x;
    if (z < 3) {
        if (by >= 16) return;
        if (z > 0 && bx >= 8) return;
        const float* A = z == 0 ? x : (z == 1 ? wq : wp);
        char* Ab = z == 0 ? xs : (z == 1 ? wqs : wps);
        const int row = tid >> 1, half = tid & 1;
        const float* src = A + ((size_t)bx * 128 + row) * EE + by * 64 + half * 32;
        char* dst = Ab + ((size_t)(bx * 16 + by)) * 16384;
        float v[32];
        #pragma unroll
        for (int i = 0; i < 8; ++i) *(float4*)&v[i * 4] = ((const float4*)src)[i];
        u32 pk[16];
        #pragma unroll
        for (int j = 0; j < 16; ++j) pk[j] = pkbf(v[2 * j], v[2 * j + 1]);
        #pragma unroll
        for (int j = 0; j < 4; ++j)
            *(uint4*)(dst + swz(row, half * 64 + j * 16)) = *(uint4*)&pk[j * 4];
        return;
    }
    const int zz = z - 3;
    const int M = (zz >= 2) ? MM2 : MM1;
    if (bx * 64 >= M) return;
    const int isV = zz & 1;
    const float* src4[4] = { K1, V1, K2, V2 };
    char* dst4[4] = { Kb1, Vb1, Kb2, Vb2 };
    const int b = by >> 4, h = by & 15;
    char* dst = dst4[zz] + ((size_t)by * (M / 64) + bx) * 8192;
    const float* src = src4[zz] + ((size_t)b * M + (size_t)bx * 64) * EE + h * DH;
    const int m = tid >> 2, q = tid & 3;
    const float* s = src + (size_t)m * EE + q * 16;
    float v[16];
    #pragma unroll
    for (int i = 0; i < 4; ++i) *(float4*)&v[i * 4] = ((const float4*)s)[i];
    if (!isV) {
        u32 pk[8];
        #pragma unroll
        for (int j = 0; j < 8; ++j) pk[j] = pkbf(v[2 * j] * KSCL, v[2 * j + 1] * KSCL);
        *(uint4*)(dst + swz(m, q * 32))      = *(uint4*)&pk[0];
        *(uint4*)(dst + swz(m, q * 32 + 16)) = *(uint4*)&pk[4];
    } else {
        #pragma unroll
        for (int j = 0; j < 16; ++j) T[(q * 16 + j) * 72 + m] = (u16)f2bf_bits(v[j]);
        __syncthreads();
        const int d = tid >> 2, qq = tid & 3;
        uint4 a0 = *(const uint4*)((const char*)T + d * 144 + qq * 32);
        uint4 a1 = *(const uint4*)((const char*)T + d * 144 + qq * 32 + 16);
        *(uint4*)(dst + swz(d, qq * 32))      = a0;
        *(uint4*)(dst + swz(d, qq * 32 + 16)) = a1;
    }
}

// ---------------------------------------------------------------------------
// bf16 MFMA GEMM, 512 thr / 8 waves, 128x64 tile, BK=64, grid 512 (16
// waves/CU). A+B in LDS (R14 layout: B-from-global regressed in R15 — L2
// overfetch). NEW: 3-buffer staging, prefetch depth 2, raw s_barrier +
// counted vmcnt(3) (never 0 in the main loop) — loads span 2 iterations so
// the barrier no longer exposes full L2 latency. Peeled last iter: vmcnt(0).
// FINAL: *sigmoid(gate), f32 out; else bf16 row-major (Q).
// ---------------------------------------------------------------------------
template<bool FINAL>
__global__ __launch_bounds__(512) void gemm_swz(const char* __restrict__ Ab,
                                                const char* __restrict__ Bb,
                                                void* __restrict__ Cout,
                                                const float* __restrict__ gate)
{
    constexpr int NKT = EE / 64;
    __shared__ char As[3][16384];
    __shared__ char Bs[3][8192];
    const int tid = threadIdx.x, lane = tid & 63, w = tid >> 6;
    const int wr = w >> 1, wc = w & 1, g = lane >> 4, ln = lane & 15;
    int lin = blockIdx.y * 32 + blockIdx.x;            // 0..511
    lin = (lin & 7) * 64 + (lin >> 3);                 // bijective XCD chunking
    const int bmi = lin & 31, bni = lin >> 5;
    const char* Abase = Ab + (size_t)bmi * NKT * 16384;
    const char* Bbase = Bb + (size_t)(bni >> 1) * NKT * 16384 + (size_t)(bni & 1) * 8192;
    f32x4 acc[2][2] = {};

    auto stage = [&](int t, int buf) {
        const char* an = Abase + (size_t)t * 16384;
        const char* bn = Bbase + (size_t)t * 16384;
        gload16(As[buf] + tid * 16,        an + tid * 16);
        gload16(As[buf] + tid * 16 + 8192, an + tid * 16 + 8192);
        gload16(Bs[buf] + tid * 16,        bn + tid * 16);
    };
    auto compute = [&](int buf) {
        #pragma unroll
        for (int kh = 0; kh < 2; ++kh) {
            bf16x8 af[2], bf2[2];
            #pragma unroll
            for (int i = 0; i < 2; ++i)
                af[i] = *(const bf16x8*)(As[buf] + swz(wr * 32 + i * 16 + ln, kh * 64 + g * 16));
            #pragma unroll
            for (int j = 0; j < 2; ++j)
                bf2[j] = *(const bf16x8*)(Bs[buf] + swz(wc * 32 + j * 16 + ln, kh * 64 + g * 16));
            #pragma unroll
            for (int i = 0; i < 2; ++i)
                #pragma unroll
                for (int j = 0; j < 2; ++j)
                    acc[i][j] = __builtin_amdgcn_mfma_f32_16x16x32_bf16(af[i], bf2[j], acc[i][j], 0, 0, 0);
        }
    };

    stage(0, 0);
    stage(1, 1);
    for (int kt = 0; kt < NKT - 1; ++kt) {
        asm volatile("s_waitcnt vmcnt(3)" ::: "memory");   // tile kt landed; kt+1 stays in flight
        __builtin_amdgcn_s_barrier();                      // all waves done reading buf[(kt+2)%3]
        __builtin_amdgcn_sched_barrier(0);
        if (kt + 2 < NKT) stage(kt + 2, (kt + 2) % 3);
        compute(kt % 3);
    }
    asm volatile("s_waitcnt vmcnt(0)" ::: "memory");       // final tile
    __builtin_amdgcn_s_barrier();
    __builtin_amdgcn_sched_barrier(0);
    compute((NKT - 1) % 3);

    float alpha = 1.0f;
    if constexpr (FINAL) alpha = 1.0f / (1.0f + __expf(-gate[0]));
    #pragma unroll
    for (int i = 0; i < 2; ++i)
        #pragma unroll
        for (int r = 0; r < 4; ++r) {
            const int row = bmi * 128 + wr * 32 + i * 16 + g * 4 + r;
            #pragma unroll
            for (int j = 0; j < 2; ++j) {
                const int col = bni * 64 + wc * 32 + j * 16 + ln;
                if constexpr (FINAL) ((float*)Cout)[(size_t)row * EE + col] = acc[i][j][r] * alpha;
                else ((u16*)Cout)[(size_t)row * EE + col] = (u16)f2bf_bits(acc[i][j][r]);
            }
        }
}

// ---------------------------------------------------------------------------
// Fused two-source attention, 8 waves x 16 q-rows (512 threads), R9/R14
// compute structure. NEW: 3-buffer K+V staging with prefetch depth 2 and
// counted vmcnt(2) at a raw s_barrier (vmcnt(0) only in the peeled final
// tile) — same mechanism as the GEMM above.
// ---------------------------------------------------------------------------
__global__ __launch_bounds__(512) void attn2(const u16* __restrict__ Qb,
                                             const char* __restrict__ Kb1, const char* __restrict__ Vb1,
                                             const char* __restrict__ Kb2, const char* __restrict__ Vb2,
                                             char* __restrict__ Ctxs)
{
    __shared__ char KV[3][16384];        // per buf: +0 K tile (8KB), +8192 V^T tile (8KB)
    __shared__ char Ps[8][2048];         // per-wave P: 16 t-rows x 128B, swizzled
    const int tid = threadIdx.x, lane = tid & 63, w = tid >> 6;
    const int g = lane >> 4, ln = lane & 15;
    const int lnx = (ln & 7) << 4;
    int lin = blockIdx.y * 16 + blockIdx.x;            // 0..511
    lin = (lin & 7) * 64 + (lin >> 3);                 // XCD chunking: 4 bh per XCD
    const int bx = lin & 15, bh = lin >> 4;
    const int b = bh >> 4, h = bh & 15;
    const int t0 = bx * 128;
    constexpr int NT1 = MM1 / 64, NT = NT1 + MM2 / 64; // 16, 20

    bf16x8 qf[2];
    #pragma unroll
    for (int kh = 0; kh < 2; ++kh)
        qf[kh] = *(const bf16x8*)(Qb + ((size_t)(b * TT + t0 + w * 16 + ln)) * EE
                                  + h * DH + kh * 32 + g * 8);

    const char* Kbase[2] = { Kb1 + (size_t)bh * (MM1 / 64) * 8192, Kb2 + (size_t)bh * (MM2 / 64) * 8192 };
    const char* Vbase[2] = { Vb1 + (size_t)bh * (MM1 / 64) * 8192, Vb2 + (size_t)bh * (MM2 / 64) * 8192 };

    f32x4 oacc[4] = {}, outacc[4] = {};
    float psum = 0.0f;

    auto stage = [&](int t, int buf) {
        const int p = (t >= NT1) ? 1 : 0, mt = p ? t - NT1 : t;
        gload16(KV[buf] + tid * 16,        Kbase[p] + (size_t)mt * 8192 + tid * 16);
        gload16(KV[buf] + 8192 + tid * 16, Vbase[p] + (size_t)mt * 8192 + tid * 16);
    };
    auto compute = [&](int buf, int ti) {
        // ---- QK^T swapped: s[f] = S^T[m = f*16+4g+r][t = w*16+ln]
        f32x4 s[4] = {};
        __builtin_amdgcn_s_setprio(1);
        #pragma unroll
        for (int kh = 0; kh < 2; ++kh)
            #pragma unroll
            for (int f = 0; f < 4; ++f) {
                const bf16x8 kf = *(const bf16x8*)(KV[buf] + swz(f * 16 + ln, kh * 64 + g * 16));
                s[f] = __builtin_amdgcn_mfma_f32_16x16x32_bf16(kf, qf[kh], s[f], 0, 0, 0);
            }
        __builtin_amdgcn_s_setprio(0);
        // ---- static softmax: p = exp2(s) (scale folded into K); pack along m
        #pragma unroll
        for (int f = 0; f < 4; ++f) {
            const float p0 = fexp2(s[f][0]);
            const float p1 = fexp2(s[f][1]);
            const float p2 = fexp2(s[f][2]);
            const float p3 = fexp2(s[f][3]);
            psum += (p0 + p1) + (p2 + p3);
            uint2 w2; w2.x = pkbf(p0, p1); w2.y = pkbf(p2, p3);
            *(uint2*)(Ps[w] + ln * 128 + ((f * 32 + g * 8) ^ lnx)) = w2;
        }
        // ---- PV: oacc[f][r] = O[t = w*16+ln][d = f*16+4g+r]
        __builtin_amdgcn_s_setprio(1);
        #pragma unroll
        for (int ks = 0; ks < 2; ++ks) {
            const bf16x8 pf = *(const bf16x8*)(Ps[w] + ln * 128 + ((ks * 64 + g * 16) ^ lnx));
            #pragma unroll
            for (int f = 0; f < 4; ++f) {
                const bf16x8 vf = *(const bf16x8*)(KV[buf] + 8192 + swz(f * 16 + ln, ks * 64 + g * 16));
                oacc[f] = __builtin_amdgcn_mfma_f32_16x16x32_bf16(vf, pf, oacc[f], 0, 0, 0);
            }
        }
        __builtin_amdgcn_s_setprio(0);
        // ---- pass boundary: normalize (2 shfl) and reset
        if (ti == NT1 - 1 || ti == NT - 1) {
            float t = psum;
            t += __shfl_xor(t, 16);
            t += __shfl_xor(t, 32);
            const float inv = 1.0f / t;
            #pragma unroll
            for (int f = 0; f < 4; ++f)
                #pragma unroll
                for (int r = 0; r < 4; ++r) {
                    outacc[f][r] += oacc[f][r] * inv;
                    oacc[f][r] = 0.0f;
                }
            psum = 0.0f;
        }
    };

    stage(0, 0);
    stage(1, 1);
    for (int ti = 0; ti < NT - 1; ++ti) {
        asm volatile("s_waitcnt vmcnt(2)" ::: "memory");   // tile ti landed; ti+1 in flight
        __builtin_amdgcn_s_barrier();                      // buf[(ti+2)%3] free to overwrite
        __builtin_amdgcn_sched_barrier(0);
        if (ti + 2 < NT) stage(ti + 2, (ti + 2) % 3);
        compute(ti % 3, ti);
    }
    asm volatile("s_waitcnt vmcnt(0)" ::: "memory");
    __builtin_amdgcn_s_barrier();
    __builtin_amdgcn_sched_barrier(0);
    compute((NT - 1) % 3, NT - 1);

    // ---- epilogue: swizzled ctx blob in LDS (16KB = KV[0]), then linear copy
    __syncthreads();
    char* eb = &KV[0][0];
    #pragma unroll
    for (int f = 0; f < 4; ++f) {
        uint2 w2;
        w2.x = pkbf(outacc[f][0], outacc[f][1]);
        w2.y = pkbf(outacc[f][2], outacc[f][3]);
        *(uint2*)(eb + (w * 16 + ln) * 128 + ((f * 32 + g * 8) ^ lnx)) = w2;
    }
    __syncthreads();
    char* blob = Ctxs + ((size_t)((b * 16 + bx) * 16 + h)) * 16384;
    #pragma unroll
    for (int i = 0; i < 2; ++i)
        *(uint4*)(blob + tid * 16 + i * 8192) = *(const uint4*)(eb + tid * 16 + i * 8192);
}

// ---------------------------------------------------------------------------
extern "C" void kernel_launch(void* const* d_in, const int* in_sizes, int n_in,
                              void* d_out, int out_size, void* d_ws, size_t ws_size,
                              hipStream_t stream) {
    const float* x    = (const float*)d_in[0];
    const float* K1   = (const float*)d_in[1];
    const float* V1   = (const float*)d_in[2];
    const float* K2   = (const float*)d_in[3];
    const float* V2   = (const float*)d_in[4];
    const float* Wq   = (const float*)d_in[5];
    const float* Wp   = (const float*)d_in[6];
    const float* gate = (const float*)d_in[7];
    float* out = (float*)d_out;

    char* ws  = (char*)d_ws;
    char* Xs  = ws;                        // 8MB swizzled x; later reused as ctx blobs
    char* Wqs = ws + (8u  << 20);          // 2MB
    char* Wps = ws + (10u << 20);          // 2MB
    u16*  Qb  = (u16*)(ws + (12u << 20));  // 8MB bf16 Q (row-major)
    char* Kb1 = ws + (20u << 20);          // 4MB
    char* Vb1 = ws + (24u << 20);          // 4MB
    char* Kb2 = ws + (28u << 20);          // 1MB
    char* Vb2 = ws + (29u << 20);          // 1MB  (total 30MB)

    dim3 blk(256);
    conv_all<<<dim3(32, 32, 7), blk, 0, stream>>>(x, Wq, Wp, K1, V1, K2, V2,
                                                  Xs, Wqs, Wps, Kb1, Vb1, Kb2, Vb2);
    gemm_swz<false><<<dim3(32, 16), dim3(512), 0, stream>>>(Xs, Wqs, Qb, nullptr);
    attn2<<<dim3(16, 32), dim3(512), 0, stream>>>(Qb, Kb1, Vb1, Kb2, Vb2, Xs /*ctx blobs*/);
    gemm_swz<true><<<dim3(32, 16), dim3(512), 0, stream>>>(Xs, Wps, out, gate);
}